// Round 1
// 853.583 us; speedup vs baseline: 9.8835x; 9.8835x over previous
//
#include <hip/hip_runtime.h>

#define NN 50000
#define NE 800000
#define FIN 128
#define FH 256
#define FOUT 40
#define NPAD 50432   // > NN+1, multiple of 64

// ---------------- CSR build: histogram, inv-sqrt degree, scan, fill ----------------

__global__ void cnt_zero_kernel(int* __restrict__ cnt) {
    int i = blockIdx.x * 256 + threadIdx.x;
    if (i < NN) cnt[i] = 0;
}

__global__ void cnt_count_kernel(int* __restrict__ cnt, const int* __restrict__ dst) {
    int e = blockIdx.x * 256 + threadIdx.x;
    if (e < NE) atomicAdd(&cnt[dst[e]], 1);
}

__global__ void inv_kernel(const int* __restrict__ cnt, float* __restrict__ inv) {
    int i = blockIdx.x * 256 + threadIdx.x;
    if (i < NN) inv[i] = rsqrtf((float)(cnt[i] + 1));   // +1 self-loop
}

// Single-block exclusive scan over cnt[NN] -> row_start, cursor.
__global__ __launch_bounds__(1024) void scan_kernel(const int* __restrict__ cnt,
                                                    int* __restrict__ row_start,
                                                    int* __restrict__ cursor) {
    __shared__ int part[1024];
    const int t = threadIdx.x;
    const int CH = (NN + 1023) / 1024;   // 49
    int lo = t * CH;
    int hi = lo + CH; if (hi > NN) hi = NN;
    int s = 0;
    for (int i = lo; i < hi; ++i) s += cnt[i];
    part[t] = s;
    __syncthreads();
    // in-place inclusive Hillis-Steele scan
    for (int off = 1; off < 1024; off <<= 1) {
        int v = (t >= off) ? part[t - off] : 0;
        __syncthreads();
        part[t] += v;
        __syncthreads();
    }
    int base = part[t] - s;   // exclusive prefix for this chunk
    for (int i = lo; i < hi; ++i) {
        row_start[i] = base;
        cursor[i]    = base;
        base += cnt[i];
    }
    if (t == 0) row_start[NN] = NE;
}

// edata[pos] = {src index (bitcast), coef = inv[s]*inv[d]} sorted by dst.
__global__ void fill_kernel(const int* __restrict__ src, const int* __restrict__ dst,
                            const float* __restrict__ inv,
                            int* __restrict__ cursor, float2* __restrict__ edata) {
    int e = blockIdx.x * 256 + threadIdx.x;
    if (e >= NE) return;
    int s = src[e];
    int d = dst[e];
    int pos = atomicAdd(&cursor[d], 1);
    edata[pos] = make_float2(__int_as_float(s), inv[s] * inv[d]);
}

// ---------------- GEMM: C[M,N] = (relu?)A[M,K] @ B[K,N] ----------------
// BM=BN=64, BK=16, 256 threads, 4x4 microtile per thread.

template<bool RELU_IN>
__global__ __launch_bounds__(256) void gemm_kernel(const float* __restrict__ A,
                                                   const float* __restrict__ B,
                                                   float* __restrict__ C,
                                                   int M, int K, int N) {
    __shared__ float As[16][68];  // [k][m], padded
    __shared__ float Bs[16][68];  // [k][n], padded (float4-aligned rows)

    const int tid = threadIdx.x;
    const int tx = tid & 15;       // 0..15 -> col group
    const int ty = tid >> 4;       // 0..15 -> row group
    const int row0 = blockIdx.x * 64;
    const int col0 = blockIdx.y * 64;

    float acc[4][4] = {};

    for (int k0 = 0; k0 < K; k0 += 16) {
        // A tile: 64 rows x 16 k. Each thread loads one float4 along K.
        {
            int r  = tid >> 2;            // 0..63
            int kc = (tid & 3) * 4;       // 0,4,8,12
            int grow = row0 + r;
            float4 v = make_float4(0.f, 0.f, 0.f, 0.f);
            if (grow < M)
                v = *reinterpret_cast<const float4*>(A + (size_t)grow * K + k0 + kc);
            if (RELU_IN) {
                v.x = fmaxf(v.x, 0.f); v.y = fmaxf(v.y, 0.f);
                v.z = fmaxf(v.z, 0.f); v.w = fmaxf(v.w, 0.f);
            }
            As[kc + 0][r] = v.x;
            As[kc + 1][r] = v.y;
            As[kc + 2][r] = v.z;
            As[kc + 3][r] = v.w;
        }
        // B tile: 16 k x 64 n. Each thread loads one float4 along N.
        {
            int kr = tid >> 4;            // 0..15
            int nc = (tid & 15) * 4;      // 0..60
            float4 v = *reinterpret_cast<const float4*>(B + (size_t)(k0 + kr) * N + col0 + nc);
            *reinterpret_cast<float4*>(&Bs[kr][nc]) = v;
        }
        __syncthreads();

        #pragma unroll
        for (int kk = 0; kk < 16; ++kk) {
            float4 a4 = *reinterpret_cast<const float4*>(&As[kk][ty * 4]);
            float4 b4 = *reinterpret_cast<const float4*>(&Bs[kk][tx * 4]);
            float a[4] = {a4.x, a4.y, a4.z, a4.w};
            float b[4] = {b4.x, b4.y, b4.z, b4.w};
            #pragma unroll
            for (int i = 0; i < 4; ++i)
                #pragma unroll
                for (int j = 0; j < 4; ++j)
                    acc[i][j] += a[i] * b[j];
        }
        __syncthreads();
    }

    #pragma unroll
    for (int i = 0; i < 4; ++i) {
        int gr = row0 + ty * 4 + i;
        if (gr < M) {
            float4 o = make_float4(acc[i][0], acc[i][1], acc[i][2], acc[i][3]);
            *reinterpret_cast<float4*>(C + (size_t)gr * N + col0 + tx * 4) = o;
        }
    }
}

// ---------------- gather: agg[d,:] = sum_e lin[src,:]*coef + lin[d,:]*inv[d]^2 + bias ----------------
// One wave per destination node; lane handles 4 consecutive features (64*4 = 256).

__global__ __launch_bounds__(256) void gather_kernel(const float* __restrict__ lin,
                                                     const float2* __restrict__ edata,
                                                     const int* __restrict__ row_start,
                                                     const float* __restrict__ inv,
                                                     const float* __restrict__ bias,
                                                     float* __restrict__ out) {
    int node = blockIdx.x * 4 + (threadIdx.x >> 6);
    int lane = threadIdx.x & 63;
    if (node >= NN) return;

    int beg = row_start[node];
    int end = row_start[node + 1];

    float iv = inv[node];
    float c  = iv * iv;                           // self-loop weight 1/deg
    float4 v = *reinterpret_cast<const float4*>(lin + (size_t)node * FH + lane * 4);
    float4 b = *reinterpret_cast<const float4*>(bias + lane * 4);
    float4 acc = make_float4(v.x * c + b.x, v.y * c + b.y, v.z * c + b.z, v.w * c + b.w);

    for (int i = beg; i < end; ++i) {
        float2 ed = edata[i];                     // wave-uniform 8B broadcast
        int   s  = __float_as_int(ed.x);
        float cf = ed.y;
        float4 w = *reinterpret_cast<const float4*>(lin + (size_t)s * FH + lane * 4);
        acc.x += w.x * cf;
        acc.y += w.y * cf;
        acc.z += w.z * cf;
        acc.w += w.w * cf;
    }

    *reinterpret_cast<float4*>(out + (size_t)node * FH + lane * 4) = acc;
}

// ---------------- mean pool + head ----------------

__global__ void colsum_zero_kernel(float* __restrict__ colsum) {
    colsum[threadIdx.x] = 0.0f;
}

__global__ void colsum_kernel(const float* __restrict__ h, float* __restrict__ colsum) {
    int f = threadIdx.x;                 // 256 features
    int r0 = blockIdx.x * 256;
    int r1 = r0 + 256; if (r1 > NN) r1 = NN;
    float s = 0.0f;
    for (int r = r0; r < r1; ++r) s += h[(size_t)r * FH + f];
    unsafeAtomicAdd(&colsum[f], s);
}

__global__ void head_kernel(const float* __restrict__ colsum,
                            const float* __restrict__ Wh,
                            const float* __restrict__ bh,
                            float* __restrict__ out) {
    int o = threadIdx.x;
    if (o >= FOUT) return;
    const float scale = 1.0f / (float)NN;
    float s = 0.0f;
    for (int f = 0; f < FH; ++f)
        s += colsum[f] * scale * Wh[f * FOUT + o];
    out[o] = s + bh[o];
}

// ---------------- launch ----------------

extern "C" void kernel_launch(void* const* d_in, const int* in_sizes, int n_in,
                              void* d_out, int out_size, void* d_ws, size_t ws_size,
                              hipStream_t stream) {
    const float* x   = (const float*)d_in[0];
    const int*   ei  = (const int*)d_in[1];
    const float* W0  = (const float*)d_in[2];
    const float* b0  = (const float*)d_in[3];
    const float* W1  = (const float*)d_in[4];
    const float* b1  = (const float*)d_in[5];
    const float* W2  = (const float*)d_in[6];
    const float* b2  = (const float*)d_in[7];
    const float* Wh  = (const float*)d_in[8];
    const float* bh  = (const float*)d_in[9];
    float* out = (float*)d_out;

    const int* src = ei;        // edge_index[0,:]
    const int* dst = ei + NE;   // edge_index[1,:]

    // workspace layout (all offsets multiples of 64 floats -> 256B aligned)
    float*  inv       = (float*)d_ws;                   // NPAD floats
    int*    cnt       = (int*)(inv + NPAD);             // NPAD ints
    int*    row_start = cnt + NPAD;                     // NN+1 used
    int*    cursor    = row_start + NPAD;               // NN used
    float2* edata     = (float2*)(cursor + NPAD);       // NE float2 (6.4 MB)
    float*  colsum    = (float*)(edata + NE);           // 256 floats
    float*  lin       = colsum + 256;                   // NN*FH
    float*  acc       = lin + (size_t)NN * FH;          // NN*FH

    const int nblk_n = (NN + 255) / 256;
    const int nblk_e = (NE + 255) / 256;
    const dim3 gemm_grid((NN + 63) / 64, FH / 64);
    const int nblk_g = (NN + 3) / 4;                    // 4 waves (nodes) per block

    // ---- CSR build (once per launch, reused by 3 layers) ----
    cnt_zero_kernel<<<nblk_n, 256, 0, stream>>>(cnt);
    cnt_count_kernel<<<nblk_e, 256, 0, stream>>>(cnt, dst);
    inv_kernel<<<nblk_n, 256, 0, stream>>>(cnt, inv);
    scan_kernel<<<1, 1024, 0, stream>>>(cnt, row_start, cursor);
    fill_kernel<<<nblk_e, 256, 0, stream>>>(src, dst, inv, cursor, edata);

    // layer 0: x[NN,FIN] @ W0 -> lin; gather -> acc
    gemm_kernel<false><<<gemm_grid, 256, 0, stream>>>(x, W0, lin, NN, FIN, FH);
    gather_kernel<<<nblk_g, 256, 0, stream>>>(lin, edata, row_start, inv, b0, acc);

    // layer 1: relu(acc) @ W1 -> lin; gather -> acc
    gemm_kernel<true><<<gemm_grid, 256, 0, stream>>>(acc, W1, lin, NN, FH, FH);
    gather_kernel<<<nblk_g, 256, 0, stream>>>(lin, edata, row_start, inv, b1, acc);

    // layer 2: relu(acc) @ W2 -> lin; gather -> acc
    gemm_kernel<true><<<gemm_grid, 256, 0, stream>>>(acc, W2, lin, NN, FH, FH);
    gather_kernel<<<nblk_g, 256, 0, stream>>>(lin, edata, row_start, inv, b2, acc);

    // global mean pool + head
    colsum_zero_kernel<<<1, 256, 0, stream>>>(colsum);
    colsum_kernel<<<(NN + 255) / 256, 256, 0, stream>>>(acc, colsum);
    head_kernel<<<1, 64, 0, stream>>>(colsum, Wh, bh, out);
}